// Round 1
// baseline (1296.421 us; speedup 1.0000x reference)
//
#include <hip/hip_runtime.h>

// RGCN: N=50000 nodes, E=600000 edges, D=64, R=65 relations, L=2 layers.
// out_i = relu( sum_r mean_{j in N_r(i)} x_j@W_r + x_i@root + b ) + relu( x_i@res_W + res_b )
// mean is linear -> per-edge transform then scatter with 1/cnt scaling.

constexpr int NN = 50000;
constexpr int EE = 600000;
constexpr int DIM = 64;
constexpr int RR = 65;

__global__ __launch_bounds__(256) void count_k(const int* __restrict__ dst,
                                               const int* __restrict__ et,
                                               int* __restrict__ cnt, int E) {
  int e = blockIdx.x * 256 + threadIdx.x;
  if (e < E) atomicAdd(&cnt[dst[e] * RR + et[e]], 1);
}

// 16 lanes per edge; each lane computes 4 output columns via float4 W loads.
__global__ __launch_bounds__(256) void edge_k(const float* __restrict__ h,
                                              const int* __restrict__ src,
                                              const int* __restrict__ dst,
                                              const int* __restrict__ et,
                                              const float* __restrict__ W,
                                              const int* __restrict__ cnt,
                                              float* __restrict__ accum, int E) {
  __shared__ float xs[16][68];           // stride 68: broadcast reads conflict-free, 16B-aligned rows
  const int g  = threadIdx.x >> 4;       // edge group within block (0..15)
  const int li = threadIdx.x & 15;       // lane within group
  const int e  = blockIdx.x * 16 + g;
  if (e >= E) return;                    // grid is exact (600000 % 16 == 0); no barrier used
  const int s = src[e], d = dst[e], t = et[e];

  *reinterpret_cast<float4*>(&xs[g][li * 4]) =
      *reinterpret_cast<const float4*>(h + (size_t)s * DIM + li * 4);

  const float* Wt = W + (size_t)t * (DIM * DIM) + li * 4;
  float a0 = 0.f, a1 = 0.f, a2 = 0.f, a3 = 0.f;
#pragma unroll 8
  for (int k = 0; k < DIM; ++k) {
    const float xd = xs[g][k];           // LDS broadcast within 16-lane group
    const float4 w = *reinterpret_cast<const float4*>(Wt + k * DIM);
    a0 += xd * w.x; a1 += xd * w.y; a2 += xd * w.z; a3 += xd * w.w;
  }
  const float sc = 1.0f / (float)cnt[d * RR + t];
  float* o = accum + (size_t)d * DIM + li * 4;
  unsafeAtomicAdd(o + 0, a0 * sc);       // native global_atomic_add_f32
  unsafeAtomicAdd(o + 1, a1 * sc);
  unsafeAtomicAdd(o + 2, a2 * sc);
  unsafeAtomicAdd(o + 3, a3 * sc);
}

// In-place finalize: io starts as the scattered conv sum, ends as next h.
__global__ __launch_bounds__(256) void node_k(const float* __restrict__ h,
                                              const float* __restrict__ root,
                                              const float* __restrict__ bias,
                                              const float* __restrict__ rw,
                                              const float* __restrict__ rb,
                                              float* __restrict__ io, int N) {
  __shared__ float xs[16][68];
  const int g  = threadIdx.x >> 4;
  const int li = threadIdx.x & 15;
  const int n  = blockIdx.x * 16 + g;
  if (n >= N) return;                    // grid exact (50000 % 16 = 0? -> 50000/16=3125 exact)

  *reinterpret_cast<float4*>(&xs[g][li * 4]) =
      *reinterpret_cast<const float4*>(h + (size_t)n * DIM + li * 4);

  float r0 = 0.f, r1 = 0.f, r2 = 0.f, r3 = 0.f;
  float s0 = 0.f, s1 = 0.f, s2 = 0.f, s3 = 0.f;
#pragma unroll 8
  for (int k = 0; k < DIM; ++k) {
    const float hd = xs[g][k];
    const float4 w = *reinterpret_cast<const float4*>(root + k * DIM + li * 4);
    const float4 v = *reinterpret_cast<const float4*>(rw   + k * DIM + li * 4);
    r0 += hd * w.x; r1 += hd * w.y; r2 += hd * w.z; r3 += hd * w.w;
    s0 += hd * v.x; s1 += hd * v.y; s2 += hd * v.z; s3 += hd * v.w;
  }
  float* o = io + (size_t)n * DIM + li * 4;
  const float4 acc = *reinterpret_cast<const float4*>(o);
  const float4 b   = *reinterpret_cast<const float4*>(bias + li * 4);
  const float4 c   = *reinterpret_cast<const float4*>(rb + li * 4);
  float o0 = fmaxf(acc.x + r0 + b.x, 0.f) + fmaxf(s0 + c.x, 0.f);
  float o1 = fmaxf(acc.y + r1 + b.y, 0.f) + fmaxf(s1 + c.y, 0.f);
  float o2 = fmaxf(acc.z + r2 + b.z, 0.f) + fmaxf(s2 + c.z, 0.f);
  float o3 = fmaxf(acc.w + r3 + b.w, 0.f) + fmaxf(s3 + c.w, 0.f);
  *reinterpret_cast<float4*>(o) = make_float4(o0, o1, o2, o3);
}

extern "C" void kernel_launch(void* const* d_in, const int* in_sizes, int n_in,
                              void* d_out, int out_size, void* d_ws, size_t ws_size,
                              hipStream_t stream) {
  const float* x    = (const float*)d_in[0];
  const int*   ei   = (const int*)d_in[1];   // [2, E]: row 0 = src, row 1 = dst
  const int*   et   = (const int*)d_in[2];
  const float* W    = (const float*)d_in[3]; // [L, R, D, D]
  const float* root = (const float*)d_in[4]; // [L, D, D]
  const float* bias = (const float*)d_in[5]; // [L, D]
  const float* resW = (const float*)d_in[6]; // [L, D, D]
  const float* resb = (const float*)d_in[7]; // [L, D]
  float* out = (float*)d_out;

  const int* src = ei;
  const int* dstp = ei + EE;

  char* ws = (char*)d_ws;
  int*   cnt = (int*)ws;                                   // 50000*65*4 = 13,000,000 B
  float* h1  = (float*)(ws + (size_t)NN * RR * sizeof(int)); // 12,800,000 B (offset 64B-aligned)

  hipMemsetAsync(cnt, 0, (size_t)NN * RR * sizeof(int), stream);
  hipMemsetAsync(h1, 0, (size_t)NN * DIM * sizeof(float), stream);
  hipMemsetAsync(out, 0, (size_t)NN * DIM * sizeof(float), stream);

  count_k<<<(EE + 255) / 256, 256, 0, stream>>>(dstp, et, cnt, EE);

  // Layer 0: x -> h1
  edge_k<<<(EE + 15) / 16, 256, 0, stream>>>(x, src, dstp, et, W, cnt, h1, EE);
  node_k<<<(NN + 15) / 16, 256, 0, stream>>>(x, root, bias, resW, resb, h1, NN);

  // Layer 1: h1 -> out
  edge_k<<<(EE + 15) / 16, 256, 0, stream>>>(h1, src, dstp, et,
                                             W + (size_t)RR * DIM * DIM, cnt, out, EE);
  node_k<<<(NN + 15) / 16, 256, 0, stream>>>(h1, root + DIM * DIM, bias + DIM,
                                             resW + DIM * DIM, resb + DIM, out, NN);
}